// Round 7
// baseline (7101.476 us; speedup 1.0000x reference)
//
#include <hip/hip_runtime.h>
#include <hip/hip_fp16.h>

#define LOG2PI_F 1.8378770664093453f

typedef _Float16 hf8_t __attribute__((ext_vector_type(8)));
typedef float f32x4_t __attribute__((ext_vector_type(4)));

__device__ __forceinline__ unsigned int packh2(float lo, float hi) {
  unsigned int l = (unsigned int)__half_as_ushort(__float2half(lo));
  unsigned int h = (unsigned int)__half_as_ushort(__float2half(hi));
  return (h << 16) | l;
}

__device__ __forceinline__ float sigmoid_f(float x) { return 1.f / (1.f + __expf(-x)); }
__device__ __forceinline__ float silu_f(float x) { return x * sigmoid_f(x); }
__device__ __forceinline__ float softplus_f(float x) {
  return fmaxf(x, 0.f) + log1pf(__expf(-fabsf(x)));
}
__device__ __forceinline__ float tanh_f(float x) {
  float ax = fabsf(x);
  float e = __expf(2.f * ax);
  return copysignf(1.f - 2.f / (e + 1.f), x);
}

// ---------------- prep kernels ----------------
__global__ void transpose_k(const float* __restrict__ in, float* __restrict__ out,
                            int R, int C) {
  int i = blockIdx.x * 256 + threadIdx.x;
  if (i < R * C) {
    int r = i / C, c = i % C;
    out[c * R + r] = in[i];
  }
}

// W_hh [768,256] fp32 -> MFMA A-fragments for the wave-owns-32-dims mapping.
// uint4 index: ((w*6 + mt)*8 + kt)*64 + lane.  mt: 0,1=r half0/1; 2,3=z; 4,5=n.
// Lane l holds A[row][k]: row = gate*256 + 32w + 16*(mt&1) + (l&15),
// k = 32kt + 8*(l>>4) + j (j=0..7); dword d packs pairs (2d,2d+1).
__global__ void whh_mfma_pack(const float* __restrict__ W, unsigned int* __restrict__ Wmf) {
  int idx = blockIdx.x * 256 + threadIdx.x;  // dword index
  if (idx < 98304) {
    int d = idx & 3;
    int u4 = idx >> 2;
    int lane = u4 & 63;
    int rem = u4 >> 6;   // (w*6+mt)*8 + kt, < 384
    int kt = rem & 7;
    int mtw = rem >> 3;  // w*6+mt < 48
    int mt = mtw % 6;
    int w = mtw / 6;
    int g = mt >> 1, half = mt & 1;
    int row = g * 256 + 32 * w + 16 * half + (lane & 15);
    int col = 32 * kt + 8 * (lane >> 4) + 2 * d;
    Wmf[idx] = packh2(W[row * 256 + col], W[row * 256 + col + 1]);
  }
}

// ---------------- gi = x @ W_ih^T + b_ih (+ b_hh folded for r,z) ----------------
// Output layout per step: [w][gate][32] -> gi[t*768 + (g>>5)*96 + gate*32 + (g&31)]
__global__ void gi_gemm(const float* __restrict__ x, const float* __restrict__ WT,
                        const float* __restrict__ bih, const float* __restrict__ bhh,
                        float* __restrict__ gi) {
  int m0 = blockIdx.x * 8;
  int g = threadIdx.x;
  __shared__ float xs[8][64];
  for (int i = g; i < 512; i += 256) xs[i >> 6][i & 63] = x[m0 * 64 + i];
  __syncthreads();
  float b0 = bih[g] + bhh[g];              // r: fold b_hh
  float b1 = bih[g + 256] + bhh[g + 256];  // z: fold b_hh
  float b2 = bih[g + 512];                 // n: b_hh applied inside tanh arg
  float a0[8], a1[8], a2[8];
#pragma unroll
  for (int r = 0; r < 8; r++) { a0[r] = b0; a1[r] = b1; a2[r] = b2; }
  for (int k = 0; k < 64; k++) {
    const float* w = WT + k * 768;
    float w0 = w[g], w1 = w[g + 256], w2 = w[g + 512];
#pragma unroll
    for (int r = 0; r < 8; r++) {
      float xv = xs[r][k];
      a0[r] = fmaf(w0, xv, a0[r]);
      a1[r] = fmaf(w1, xv, a1[r]);
      a2[r] = fmaf(w2, xv, a2[r]);
    }
  }
  int wv = g >> 5, l = g & 31;
#pragma unroll
  for (int r = 0; r < 8; r++) {
    float* o = gi + (m0 + r) * 768 + wv * 96;
    o[l] = a0[r];
    o[32 + l] = a1[r];
    o[64 + l] = a2[r];
  }
}

// ---------------- GRU scan via MFMA: 512 threads = 8 waves, wave owns 32 dims ----
// D-layout alignment trick: for dim 32w+16*half+4q+e, the r/z/n dots land in the
// SAME lane (group q), reg e of acc[half], acc[2+half], acc[4+half]. Gate combine
// is pure-register; h_prev lives in registers; ONE barrier per step; no als array.
__global__ __launch_bounds__(512, 1) void gru_kernel(
    const uint4* __restrict__ Wmf,   // [8*6*8*64] uint4 A-fragments
    const float* __restrict__ gi,    // [8,2048,768] permuted, b_hh r/z folded
    const float* __restrict__ bhh,   // [768] (n bias used)
    float* __restrict__ h_seq)       // [8,2048,256]
{
  const int b = blockIdx.x;
  const int tid = threadIdx.x;
  const int w = tid >> 6;
  const int lane = tid & 63;
  const int q = lane >> 4;

  uint4 wA[48];
#pragma unroll
  for (int i = 0; i < 48; i++) wA[i] = Wmf[(w * 48 + i) * 64 + lane];

  __shared__ __align__(16) unsigned int hpk[2][128];  // h as f16[256], dbuf
  if (tid < 128) hpk[0][tid] = 0u;

  const int dbase = 32 * w + 4 * q;  // dims: dbase+e (half0), dbase+16+e (half1)
  float bn0[4], bn1[4], h0[4], h1[4];
#pragma unroll
  for (int e = 0; e < 4; e++) {
    bn0[e] = bhh[512 + dbase + e];
    bn1[e] = bhh[512 + dbase + 16 + e];
    h0[e] = 0.f;
    h1[e] = 0.f;
  }

  const float* gib = gi + b * 2048 * 768;
  float* hsb = h_seq + b * 2048 * 256;
  const float* gw0 = gib + w * 96 + 4 * q;
  float4 gr0 = *(const float4*)(gw0 + 0);
  float4 gr1 = *(const float4*)(gw0 + 16);
  float4 gz0 = *(const float4*)(gw0 + 32);
  float4 gz1 = *(const float4*)(gw0 + 48);
  float4 gn0 = *(const float4*)(gw0 + 64);
  float4 gn1 = *(const float4*)(gw0 + 80);
  __syncthreads();

  int cur = 0;
  for (int t = 0; t < 2048; t++) {
    // prefetch next step's gi (consumed next iteration; hidden under this step)
    const float* gnx = gib + min(t + 1, 2047) * 768 + w * 96 + 4 * q;
    float4 pr0 = *(const float4*)(gnx + 0);
    float4 pr1 = *(const float4*)(gnx + 16);
    float4 pz0 = *(const float4*)(gnx + 32);
    float4 pz1 = *(const float4*)(gnx + 48);
    float4 pn0 = *(const float4*)(gnx + 64);
    float4 pn1 = *(const float4*)(gnx + 80);

    // B-fragments: broadcast h (identical 16 columns); conflict-free reads
    const char* hb = (const char*)hpk[cur] + 16 * q;
    f32x4_t a0 = {0.f, 0.f, 0.f, 0.f}, a1 = a0, a2 = a0, a3 = a0, a4 = a0, a5 = a0;
#pragma unroll
    for (int kt = 0; kt < 8; kt++) {
      hf8_t bf = __builtin_bit_cast(hf8_t, *(const uint4*)(hb + 64 * kt));
      a0 = __builtin_amdgcn_mfma_f32_16x16x32_f16(
          __builtin_bit_cast(hf8_t, wA[kt]), bf, a0, 0, 0, 0);
      a1 = __builtin_amdgcn_mfma_f32_16x16x32_f16(
          __builtin_bit_cast(hf8_t, wA[8 + kt]), bf, a1, 0, 0, 0);
      a2 = __builtin_amdgcn_mfma_f32_16x16x32_f16(
          __builtin_bit_cast(hf8_t, wA[16 + kt]), bf, a2, 0, 0, 0);
      a3 = __builtin_amdgcn_mfma_f32_16x16x32_f16(
          __builtin_bit_cast(hf8_t, wA[24 + kt]), bf, a3, 0, 0, 0);
      a4 = __builtin_amdgcn_mfma_f32_16x16x32_f16(
          __builtin_bit_cast(hf8_t, wA[32 + kt]), bf, a4, 0, 0, 0);
      a5 = __builtin_amdgcn_mfma_f32_16x16x32_f16(
          __builtin_bit_cast(hf8_t, wA[40 + kt]), bf, a5, 0, 0, 0);
    }

    // in-register epilogue: 8 dims per lane (redundant across the 16 cols)
    {
      float rv, zv, nv;
      rv = sigmoid_f(a0[0] + gr0.x); zv = sigmoid_f(a2[0] + gz0.x);
      nv = tanh_f(gn0.x + rv * (a4[0] + bn0[0])); h0[0] = (1.f - zv) * nv + zv * h0[0];
      rv = sigmoid_f(a0[1] + gr0.y); zv = sigmoid_f(a2[1] + gz0.y);
      nv = tanh_f(gn0.y + rv * (a4[1] + bn0[1])); h0[1] = (1.f - zv) * nv + zv * h0[1];
      rv = sigmoid_f(a0[2] + gr0.z); zv = sigmoid_f(a2[2] + gz0.z);
      nv = tanh_f(gn0.z + rv * (a4[2] + bn0[2])); h0[2] = (1.f - zv) * nv + zv * h0[2];
      rv = sigmoid_f(a0[3] + gr0.w); zv = sigmoid_f(a2[3] + gz0.w);
      nv = tanh_f(gn0.w + rv * (a4[3] + bn0[3])); h0[3] = (1.f - zv) * nv + zv * h0[3];

      rv = sigmoid_f(a1[0] + gr1.x); zv = sigmoid_f(a3[0] + gz1.x);
      nv = tanh_f(gn1.x + rv * (a5[0] + bn1[0])); h1[0] = (1.f - zv) * nv + zv * h1[0];
      rv = sigmoid_f(a1[1] + gr1.y); zv = sigmoid_f(a3[1] + gz1.y);
      nv = tanh_f(gn1.y + rv * (a5[1] + bn1[1])); h1[1] = (1.f - zv) * nv + zv * h1[1];
      rv = sigmoid_f(a1[2] + gr1.z); zv = sigmoid_f(a3[2] + gz1.z);
      nv = tanh_f(gn1.z + rv * (a5[2] + bn1[2])); h1[2] = (1.f - zv) * nv + zv * h1[2];
      rv = sigmoid_f(a1[3] + gr1.w); zv = sigmoid_f(a3[3] + gz1.w);
      nv = tanh_f(gn1.w + rv * (a5[3] + bn1[3])); h1[3] = (1.f - zv) * nv + zv * h1[3];
    }

    if ((lane & 15) == 0) {
      float4 v0 = {h0[0], h0[1], h0[2], h0[3]};
      float4 v1 = {h1[0], h1[1], h1[2], h1[3]};
      *(float4*)&hsb[t * 256 + dbase] = v0;
      *(float4*)&hsb[t * 256 + dbase + 16] = v1;
      uint2 p0 = {packh2(h0[0], h0[1]), packh2(h0[2], h0[3])};
      uint2 p1 = {packh2(h1[0], h1[1]), packh2(h1[2], h1[3])};
      *(uint2*)&hpk[cur ^ 1][16 * w + 2 * q] = p0;
      *(uint2*)&hpk[cur ^ 1][16 * w + 8 + 2 * q] = p1;
    }

    gr0 = pr0; gr1 = pr1; gz0 = pz0; gz1 = pz1; gn0 = pn0; gn1 = pn1;
    __syncthreads();  // single barrier: hpk double-buffered
    cur ^= 1;
  }
}

// ---------------- banded softmax attention + ctx = h_global + attn ----------------
#define AW 80
__global__ void attn_kernel(const float* __restrict__ h_seq, const float* __restrict__ t,
                            float* __restrict__ ctx) {
  const int blk = blockIdx.x;
  const int b = blk >> 7;
  const int k0 = (blk & 127) << 4;  // 16 query rows per block
  const int tid = threadIdx.x;

  __shared__ __align__(16) float ewT[176][16];
  __shared__ float ts[176];
  __shared__ float tks[16];
  __shared__ float rden[16];

  const float* tb = t + b * 2048;
  if (tid < 176) {
    int j = k0 - AW + tid;
    ts[tid] = tb[min(max(j, 0), 2047)];
  }
  if (tid < 16) tks[tid] = tb[k0 + tid];
  __syncthreads();

  for (int p = tid; p < 176 * 16; p += 256) {
    int kk = p & 15, jr = p >> 4;
    int j = k0 - AW + jr;
    float d = 2048.f * (tks[kk] - ts[jr]);
    float e = (j >= 0 && j < 2048) ? __expf(-d * d) : 0.f;
    ewT[jr][kk] = e;
  }
  __syncthreads();

  if (tid < 16) {
    float s = 0.f;
    for (int jr = 0; jr < 176; jr++) s += ewT[jr][tid];
    rden[tid] = 1.f / s;
  }
  __syncthreads();

  float acc[16];
#pragma unroll
  for (int kk = 0; kk < 16; kk++) acc[kk] = 0.f;

  const float* hb = h_seq + b * 2048 * 256;
  for (int jr = 0; jr < 176; jr++) {
    int j = min(max(k0 - AW + jr, 0), 2047);
    float hv = hb[j * 256 + tid];
    const float4* e4 = (const float4*)ewT[jr];
    float4 e0 = e4[0], e1 = e4[1], e2 = e4[2], e3 = e4[3];
    acc[0] = fmaf(e0.x, hv, acc[0]);   acc[1] = fmaf(e0.y, hv, acc[1]);
    acc[2] = fmaf(e0.z, hv, acc[2]);   acc[3] = fmaf(e0.w, hv, acc[3]);
    acc[4] = fmaf(e1.x, hv, acc[4]);   acc[5] = fmaf(e1.y, hv, acc[5]);
    acc[6] = fmaf(e1.z, hv, acc[6]);   acc[7] = fmaf(e1.w, hv, acc[7]);
    acc[8] = fmaf(e2.x, hv, acc[8]);   acc[9] = fmaf(e2.y, hv, acc[9]);
    acc[10] = fmaf(e2.z, hv, acc[10]); acc[11] = fmaf(e2.w, hv, acc[11]);
    acc[12] = fmaf(e3.x, hv, acc[12]); acc[13] = fmaf(e3.y, hv, acc[13]);
    acc[14] = fmaf(e3.z, hv, acc[14]); acc[15] = fmaf(e3.w, hv, acc[15]);
  }

  float hg = hb[2047 * 256 + tid];
  float* cb = ctx + (b * 2048 + k0) * 256 + tid;
#pragma unroll
  for (int kk = 0; kk < 16; kk++) cb[kk * 256] = hg + acc[kk] * rden[kk];
}

// ---------------- init head: m0, s0, log_q0 ----------------
__global__ void init_head(const float* __restrict__ ctx, const float* __restrict__ WT1,
                          const float* __restrict__ bi1, const float* __restrict__ WT2,
                          const float* __restrict__ bi2, const float* __restrict__ eps0,
                          float* __restrict__ m0s0, float* __restrict__ lq0) {
  int b = blockIdx.x;
  int g = threadIdx.x;
  __shared__ float xs[256], his[256], ms[64], red[32];
  xs[g] = ctx[(b * 2048) * 256 + g];
  __syncthreads();
  float acc = bi1[g];
#pragma unroll 8
  for (int k = 0; k < 256; k++) acc = fmaf(WT1[k * 256 + g], xs[k], acc);
  his[g] = silu_f(acc);
  __syncthreads();
  if (g < 64) {
    float a2 = bi2[g];
#pragma unroll 8
    for (int k = 0; k < 256; k++) a2 = fmaf(WT2[k * 64 + g], his[k], a2);
    float v = (g < 32) ? a2 : (softplus_f(a2) + 1e-6f);
    m0s0[b * 64 + g] = v;
    ms[g] = v;
  }
  __syncthreads();
  if (g < 32) {
    float m = ms[g], s = ms[32 + g];
    float c0 = m + s * eps0[b * 32 + g];
    float sc = fmaxf(s, 1e-12f);
    float z = (c0 - m) / sc;
    red[g] = z * z + 2.f * __logf(sc) + LOG2PI_F;
  }
  __syncthreads();
  if (g == 0) {
    float s = 0.f;
    for (int i = 0; i < 32; i++) s += red[i];
    lq0[b] = -0.5f * s;
  }
}

// ---------------- step-head dense layer (M-tile=8) ----------------
__global__ void head_layer(const float* __restrict__ A, const float* __restrict__ WT,
                           const float* __restrict__ bias, const float* __restrict__ wext,
                           const float* __restrict__ tvec, float* __restrict__ C,
                           int N, int act) {
  int m0 = blockIdx.x * 8;
  int g = threadIdx.x;
  __shared__ __align__(16) float As[8][256];
#pragma unroll
  for (int r = 0; r < 8; r++) As[r][g] = A[(m0 + r) * 256 + g];
  __syncthreads();
  if (g < N) {
    float b0 = bias[g];
    float acc[8] = {b0, b0, b0, b0, b0, b0, b0, b0};
    for (int k4 = 0; k4 < 64; k4++) {
      const float* w = WT + (k4 * 4) * N + g;
      float w0v = w[0], w1v = w[N], w2v = w[2 * N], w3v = w[3 * N];
#pragma unroll
      for (int r = 0; r < 8; r++) {
        float4 xv = *(const float4*)(&As[r][k4 * 4]);
        acc[r] = fmaf(w0v, xv.x, acc[r]);
        acc[r] = fmaf(w1v, xv.y, acc[r]);
        acc[r] = fmaf(w2v, xv.z, acc[r]);
        acc[r] = fmaf(w3v, xv.w, acc[r]);
      }
    }
#pragma unroll
    for (int r = 0; r < 8; r++) {
      float a = acc[r];
      if (wext) a = fmaf(tvec[m0 + r], wext[g], a);
      if (act) a = silu_f(a);
      C[(m0 + r) * N + g] = a;
    }
  }
}

// ---------------- OU posterior: parallel segmented scan ----------------
__global__ __launch_bounds__(1024) void ou_kernel(
    const float* __restrict__ params, const float* __restrict__ t,
    const float* __restrict__ eps, const float* __restrict__ eps0,
    const float* __restrict__ m0s0, const float* __restrict__ lq0,
    float* __restrict__ out) {
  const int b = blockIdx.x;
  const int c = threadIdx.x & 31;
  const int s = threadIdx.x >> 5;  // segment 0..31
  const int k0 = s * 64;
  const int k1 = min(k0 + 64, 2047);
  const float* tb = t + b * 2048;

  __shared__ float Ps[32][33], Ss[32][33], Cs[32][33], lqs[32][33];

  float P = 1.f, S = 0.f, lq = 0.f;
  for (int k = k0; k < k1; k++) {
    const float* pr = params + (b * 2048 + k) * 96;
    float mu = pr[c];
    float kap = softplus_f(pr[32 + c]) + 1e-6f;
    float sg = softplus_f(pr[64 + c]) + 1e-6f;
    float dt = fmaxf(tb[k + 1] - tb[k], 1e-6f);
    float A = __expf(-kap * dt);
    float tkd = 2.f * kap * dt;
    float Qe = sg * sg * (1.f - A * A) / fmaxf(2.f * kap, 1e-12f);
    float kd = kap * dt;
    float Qt = sg * sg * dt * (1.f - kd + tkd * tkd * (1.f / 6.f));
    float var = fmaxf((tkd < 1e-6f) ? Qt : Qe, 1e-12f);
    float e = eps[(b * 2047 + k) * 32 + c];
    float d = mu * (1.f - A) + e * sqrtf(var);
    S = fmaf(A, S, d);
    P *= A;
    lq += e * e + __logf(var) + LOG2PI_F;
  }
  Ps[c][s] = P;
  Ss[c][s] = S;
  lqs[c][s] = lq;
  __syncthreads();

  if (s == 0) {
    float m0v = m0s0[b * 64 + c];
    float s0v = m0s0[b * 64 + 32 + c];
    float cc = fmaf(s0v, eps0[b * 32 + c], m0v);
    out[(b * 2048) * 32 + c] = cc;
    float lqt = 0.f;
    for (int i = 0; i < 32; i++) {
      Cs[c][i] = cc;
      cc = fmaf(Ps[c][i], cc, Ss[c][i]);
      lqt += lqs[c][i];
    }
    for (int off = 16; off >= 1; off >>= 1) lqt += __shfl_down(lqt, off, 32);
    if (c == 0) out[8 * 2048 * 32 + b] = lq0[b] - 0.5f * lqt;
  }
  __syncthreads();

  float cc = Cs[c][s];
  for (int k = k0; k < k1; k++) {
    const float* pr = params + (b * 2048 + k) * 96;
    float mu = pr[c];
    float kap = softplus_f(pr[32 + c]) + 1e-6f;
    float sg = softplus_f(pr[64 + c]) + 1e-6f;
    float dt = fmaxf(tb[k + 1] - tb[k], 1e-6f);
    float A = __expf(-kap * dt);
    float tkd = 2.f * kap * dt;
    float Qe = sg * sg * (1.f - A * A) / fmaxf(2.f * kap, 1e-12f);
    float kd = kap * dt;
    float Qt = sg * sg * dt * (1.f - kd + tkd * tkd * (1.f / 6.f));
    float var = fmaxf((tkd < 1e-6f) ? Qt : Qe, 1e-12f);
    float e = eps[(b * 2047 + k) * 32 + c];
    float d = mu * (1.f - A) + e * sqrtf(var);
    cc = fmaf(A, cc, d);
    out[(b * 2048 + k + 1) * 32 + c] = cc;
  }
}

// ---------------- launcher ----------------
extern "C" void kernel_launch(void* const* d_in, const int* in_sizes, int n_in,
                              void* d_out, int out_size, void* d_ws, size_t ws_size,
                              hipStream_t stream) {
  (void)in_sizes; (void)n_in; (void)out_size; (void)ws_size;
  const float* x    = (const float*)d_in[0];
  const float* t    = (const float*)d_in[1];
  const float* eps0 = (const float*)d_in[2];
  const float* eps  = (const float*)d_in[3];
  const float* W_ih = (const float*)d_in[4];
  const float* W_hh = (const float*)d_in[5];
  const float* b_ih = (const float*)d_in[6];
  const float* b_hh = (const float*)d_in[7];
  const float* Wi1  = (const float*)d_in[8];
  const float* bi1  = (const float*)d_in[9];
  const float* Wi2  = (const float*)d_in[10];
  const float* bi2  = (const float*)d_in[11];
  const float* Ws1  = (const float*)d_in[12];
  const float* bs1  = (const float*)d_in[13];
  const float* Ws2  = (const float*)d_in[14];
  const float* bs2  = (const float*)d_in[15];
  const float* Ws3  = (const float*)d_in[16];
  const float* bs3  = (const float*)d_in[17];
  float* out = (float*)d_out;
  float* ws = (float*)d_ws;

  // workspace layout (float offsets)
  float*        WT_ih = ws + 0;                        // 64x768   = 49152
  unsigned int* Wmf   = (unsigned int*)(ws + 49152);   // 98304 dwords (MFMA frags)
  float*        WT1   = ws + 147456;                   // 256x256  = 65536
  float*        WT2   = ws + 212992;                   // 256x64   = 16384
  float*        WTs1  = ws + 229376;                   // 257x256  = 65792
  float*        WTs2  = ws + 295168;                   // 256x256  = 65536
  float*        WTs3  = ws + 360704;                   // 256x96   = 24576
  float*        m0s0  = ws + 385280;                   // 8x64
  float*        lq0   = ws + 385792;                   // 8
  float*        gi    = ws + 385800;                   // 8x2048x768 = 12582912
  float*        h_seq = gi + 12582912;                 // 8x2048x256 = 4194304
  float*        ctx   = h_seq + 4194304;               // 8x2048x256 = 4194304
  // reuse gi region after GRU:
  float*        hs1    = gi;                           // 4194304
  float*        hs2    = gi + 4194304;                 // 4194304
  float*        params = gi + 8388608;                 // 8x2048x96 = 1572864

  // prep
  transpose_k<<<(768 * 64 + 255) / 256, 256, 0, stream>>>(W_ih, WT_ih, 768, 64);
  transpose_k<<<(256 * 256 + 255) / 256, 256, 0, stream>>>(Wi1, WT1, 256, 256);
  transpose_k<<<(64 * 256 + 255) / 256, 256, 0, stream>>>(Wi2, WT2, 64, 256);
  transpose_k<<<(256 * 257 + 255) / 256, 256, 0, stream>>>(Ws1, WTs1, 256, 257);
  transpose_k<<<(256 * 256 + 255) / 256, 256, 0, stream>>>(Ws2, WTs2, 256, 256);
  transpose_k<<<(96 * 256 + 255) / 256, 256, 0, stream>>>(Ws3, WTs3, 96, 256);
  whh_mfma_pack<<<384, 256, 0, stream>>>(W_hh, (unsigned int*)Wmf);

  // pipeline
  gi_gemm<<<2048, 256, 0, stream>>>(x, WT_ih, b_ih, b_hh, gi);
  gru_kernel<<<8, 512, 0, stream>>>((const uint4*)Wmf, gi, b_hh, h_seq);
  attn_kernel<<<1024, 256, 0, stream>>>(h_seq, t, ctx);
  init_head<<<8, 256, 0, stream>>>(ctx, WT1, bi1, WT2, bi2, eps0, m0s0, lq0);
  head_layer<<<2048, 256, 0, stream>>>(ctx, WTs1, bs1, WTs1 + 256 * 256, t, hs1, 256, 1);
  head_layer<<<2048, 256, 0, stream>>>(hs1, WTs2, bs2, nullptr, nullptr, hs2, 256, 1);
  head_layer<<<2048, 256, 0, stream>>>(hs2, WTs3, bs3, nullptr, nullptr, params, 96, 0);
  ou_kernel<<<8, 1024, 0, stream>>>(params, t, eps, eps0, m0s0, lq0, out);
}

// Round 8
// 3895.284 us; speedup vs baseline: 1.8231x; 1.8231x over previous
//
#include <hip/hip_runtime.h>
#include <hip/hip_fp16.h>

#define LOG2PI_F 1.8378770664093453f

typedef _Float16 hf8_t __attribute__((ext_vector_type(8)));
typedef float f32x4_t __attribute__((ext_vector_type(4)));

__device__ __forceinline__ unsigned int packh2(float lo, float hi) {
  unsigned int l = (unsigned int)__half_as_ushort(__float2half(lo));
  unsigned int h = (unsigned int)__half_as_ushort(__float2half(hi));
  return (h << 16) | l;
}

__device__ __forceinline__ float sigmoid_f(float x) { return 1.f / (1.f + __expf(-x)); }
__device__ __forceinline__ float silu_f(float x) { return x * sigmoid_f(x); }
__device__ __forceinline__ float softplus_f(float x) {
  return fmaxf(x, 0.f) + log1pf(__expf(-fabsf(x)));
}
__device__ __forceinline__ float tanh_f(float x) {
  float ax = fabsf(x);
  float e = __expf(2.f * ax);
  return copysignf(1.f - 2.f / (e + 1.f), x);
}

// LDS-only barrier: waits LDS ops, does NOT drain VMEM (avoids the ~900-cyc
// vmcnt(0) stall __syncthreads would force on the in-flight gi prefetch).
__device__ __forceinline__ void barrier_lds() {
  asm volatile("s_waitcnt lgkmcnt(0)" ::: "memory");
  __builtin_amdgcn_s_barrier();
  asm volatile("" ::: "memory");
}

// ---------------- prep kernels ----------------
__global__ void transpose_k(const float* __restrict__ in, float* __restrict__ out,
                            int R, int C) {
  int i = blockIdx.x * 256 + threadIdx.x;
  if (i < R * C) {
    int r = i / C, c = i % C;
    out[c * R + r] = in[i];
  }
}

// W_hh [768,256] fp32 -> MFMA A-fragment layout, f16 pairs packed in dwords.
// uint4 index u4 = (mt*8 + kt)*64 + lane  (mt = 0..47 M-tile over gate rows,
// kt = 0..7 K-tile). Lane l holds A[row = 16mt + (l&15)][k = 32kt + 8*(l>>4) + j].
__global__ void whh_mfma_pack(const float* __restrict__ W, unsigned int* __restrict__ Wmf) {
  int idx = blockIdx.x * 256 + threadIdx.x;  // dword index
  if (idx < 98304) {
    int d = idx & 3;
    int u4 = idx >> 2;
    int lane = u4 & 63;
    int rem = u4 >> 6;   // mt*8 + kt
    int kt = rem & 7;
    int mt = rem >> 3;
    int row = 16 * mt + (lane & 15);
    int col = 32 * kt + 8 * (lane >> 4) + 2 * d;
    Wmf[idx] = packh2(W[row * 256 + col], W[row * 256 + col + 1]);
  }
}

// ---------------- gi = x @ W_ih^T + b_ih (+ b_hh folded for r,z), M-tile 8 -------
__global__ void gi_gemm(const float* __restrict__ x, const float* __restrict__ WT,
                        const float* __restrict__ bih, const float* __restrict__ bhh,
                        float* __restrict__ gi) {
  int m0 = blockIdx.x * 8;
  int g = threadIdx.x;
  __shared__ float xs[8][64];
  for (int i = g; i < 512; i += 256) xs[i >> 6][i & 63] = x[m0 * 64 + i];
  __syncthreads();
  float b0 = bih[g] + bhh[g];              // r: fold b_hh
  float b1 = bih[g + 256] + bhh[g + 256];  // z: fold b_hh
  float b2 = bih[g + 512];                 // n: b_hh applied inside tanh arg
  float a0[8], a1[8], a2[8];
#pragma unroll
  for (int r = 0; r < 8; r++) { a0[r] = b0; a1[r] = b1; a2[r] = b2; }
  for (int k = 0; k < 64; k++) {
    const float* w = WT + k * 768;
    float w0 = w[g], w1 = w[g + 256], w2 = w[g + 512];
#pragma unroll
    for (int r = 0; r < 8; r++) {
      float xv = xs[r][k];
      a0[r] = fmaf(w0, xv, a0[r]);
      a1[r] = fmaf(w1, xv, a1[r]);
      a2[r] = fmaf(w2, xv, a2[r]);
    }
  }
#pragma unroll
  for (int r = 0; r < 8; r++) {
    float* o = gi + (m0 + r) * 768;
    o[g] = a0[r];
    o[g + 256] = a1[r];
    o[g + 512] = a2[r];
  }
}

// ---------------- GRU scan via MFMA: one block/batch, 768 threads = 12 waves -----
// R6 structure (verified; no spill: 128 AGPR weights + ~84 arch at 3 waves/SIMD).
// Changes vs R6: (1) raw LDS-only barriers instead of __syncthreads -> no per-step
// vmcnt(0) drain of the gi prefetch / h_seq stores; (2) 2-step-deep gi prefetch so
// the counted vmcnt wait at use is non-blocking even at ~1000-cyc steps.
__global__ __launch_bounds__(768, 3) void gru_kernel(
    const uint4* __restrict__ Wmf,   // [12*4*8*64] uint4 A-fragments
    const float* __restrict__ gi,    // [8,2048,768], b_hh r/z pre-folded
    const float* __restrict__ bhh,   // [768] (n bias used)
    float* __restrict__ h_seq)       // [8,2048,256]
{
  const int b = blockIdx.x;
  const int tid = threadIdx.x;
  const int w = tid >> 6;
  const int lane = tid & 63;
  const int q = lane >> 4;

  uint4 wA[32];
#pragma unroll
  for (int i = 0; i < 32; i++) wA[i] = Wmf[(w * 32 + i) * 64 + lane];

  __shared__ __align__(16) unsigned int hpk[2][128];  // h as f16[256], dbuf
  __shared__ __align__(16) float als[768];            // raw hh-dots
  if (tid < 128) hpk[0][tid] = 0u;

  const float* gib = gi + b * 2048 * 768;
  float* hsb = h_seq + b * 2048 * 256;

  float h = 0.f, bn = 0.f;
  float g0r = 0.f, g0z = 0.f, g0n = 0.f;  // gi for step t
  float g1r = 0.f, g1z = 0.f, g1n = 0.f;  // gi for step t+1
  if (tid < 256) {
    bn = bhh[512 + tid];
    g0r = gib[tid];
    g0z = gib[256 + tid];
    g0n = gib[512 + tid];
    const float* g1 = gib + 768;
    g1r = g1[tid];
    g1z = g1[256 + tid];
    g1n = g1[512 + tid];
  }
  __syncthreads();  // once, before the loop (full drain OK here)

  int cur = 0;
  for (int t = 0; t < 2048; t++) {
    // issue loads for step t+2 (consumed in 2 steps; hides ~900cy HBM latency)
    float g2r = 0.f, g2z = 0.f, g2n = 0.f;
    if (tid < 256) {
      const float* g2 = gib + min(t + 2, 2047) * 768;
      g2r = g2[tid];
      g2z = g2[256 + tid];
      g2n = g2[512 + tid];
    }

    // MFMA phase: B = h broadcast into all 16 columns (conflict-free reads)
    const char* hb = (const char*)hpk[cur] + 16 * q;
    f32x4_t a0 = {0.f, 0.f, 0.f, 0.f}, a1 = a0, a2 = a0, a3 = a0;
#pragma unroll
    for (int kt = 0; kt < 8; kt++) {
      hf8_t bf = __builtin_bit_cast(hf8_t, *(const uint4*)(hb + 64 * kt));
      a0 = __builtin_amdgcn_mfma_f32_16x16x32_f16(
          __builtin_bit_cast(hf8_t, wA[kt]), bf, a0, 0, 0, 0);
      a1 = __builtin_amdgcn_mfma_f32_16x16x32_f16(
          __builtin_bit_cast(hf8_t, wA[8 + kt]), bf, a1, 0, 0, 0);
      a2 = __builtin_amdgcn_mfma_f32_16x16x32_f16(
          __builtin_bit_cast(hf8_t, wA[16 + kt]), bf, a2, 0, 0, 0);
      a3 = __builtin_amdgcn_mfma_f32_16x16x32_f16(
          __builtin_bit_cast(hf8_t, wA[24 + kt]), bf, a3, 0, 0, 0);
    }
    // D: col=lane&15 (all identical), row=4*(lane>>4)+reg.
    if ((lane & 15) == 0) {
      int rbase = 64 * w + 4 * q;
      *(f32x4_t*)&als[rbase] = a0;
      *(f32x4_t*)&als[rbase + 16] = a1;
      *(f32x4_t*)&als[rbase + 32] = a2;
      *(f32x4_t*)&als[rbase + 48] = a3;
    }
    barrier_lds();  // als visible; gi loads stay in flight

    if (tid < 256) {
      float rv = sigmoid_f(als[tid] + g0r);
      float zv = sigmoid_f(als[256 + tid] + g0z);
      float nv = tanh_f(g0n + rv * (als[512 + tid] + bn));
      float hnew = (1.f - zv) * nv + zv * h;
      h = hnew;
      hsb[t * 256 + tid] = hnew;  // fire-and-forget (no drain)
      float other = __shfl_xor(hnew, 1);
      if ((tid & 1) == 0) hpk[cur ^ 1][tid >> 1] = packh2(hnew, other);
    }
    barrier_lds();  // hpk[cur^1] visible for next step's MFMA

    g0r = g1r; g0z = g1z; g0n = g1n;
    g1r = g2r; g1z = g2z; g1n = g2n;
    cur ^= 1;
  }
}

// ---------------- banded softmax attention + ctx = h_global + attn ----------------
#define AW 80
__global__ void attn_kernel(const float* __restrict__ h_seq, const float* __restrict__ t,
                            float* __restrict__ ctx) {
  const int blk = blockIdx.x;
  const int b = blk >> 7;
  const int k0 = (blk & 127) << 4;  // 16 query rows per block
  const int tid = threadIdx.x;

  __shared__ __align__(16) float ewT[176][16];
  __shared__ float ts[176];
  __shared__ float tks[16];
  __shared__ float rden[16];

  const float* tb = t + b * 2048;
  if (tid < 176) {
    int j = k0 - AW + tid;
    ts[tid] = tb[min(max(j, 0), 2047)];
  }
  if (tid < 16) tks[tid] = tb[k0 + tid];
  __syncthreads();

  for (int p = tid; p < 176 * 16; p += 256) {
    int kk = p & 15, jr = p >> 4;
    int j = k0 - AW + jr;
    float d = 2048.f * (tks[kk] - ts[jr]);
    float e = (j >= 0 && j < 2048) ? __expf(-d * d) : 0.f;
    ewT[jr][kk] = e;
  }
  __syncthreads();

  if (tid < 16) {
    float s = 0.f;
    for (int jr = 0; jr < 176; jr++) s += ewT[jr][tid];
    rden[tid] = 1.f / s;
  }
  __syncthreads();

  float acc[16];
#pragma unroll
  for (int kk = 0; kk < 16; kk++) acc[kk] = 0.f;

  const float* hb = h_seq + b * 2048 * 256;
  for (int jr = 0; jr < 176; jr++) {
    int j = min(max(k0 - AW + jr, 0), 2047);
    float hv = hb[j * 256 + tid];
    const float4* e4 = (const float4*)ewT[jr];
    float4 e0 = e4[0], e1 = e4[1], e2 = e4[2], e3 = e4[3];
    acc[0] = fmaf(e0.x, hv, acc[0]);   acc[1] = fmaf(e0.y, hv, acc[1]);
    acc[2] = fmaf(e0.z, hv, acc[2]);   acc[3] = fmaf(e0.w, hv, acc[3]);
    acc[4] = fmaf(e1.x, hv, acc[4]);   acc[5] = fmaf(e1.y, hv, acc[5]);
    acc[6] = fmaf(e1.z, hv, acc[6]);   acc[7] = fmaf(e1.w, hv, acc[7]);
    acc[8] = fmaf(e2.x, hv, acc[8]);   acc[9] = fmaf(e2.y, hv, acc[9]);
    acc[10] = fmaf(e2.z, hv, acc[10]); acc[11] = fmaf(e2.w, hv, acc[11]);
    acc[12] = fmaf(e3.x, hv, acc[12]); acc[13] = fmaf(e3.y, hv, acc[13]);
    acc[14] = fmaf(e3.z, hv, acc[14]); acc[15] = fmaf(e3.w, hv, acc[15]);
  }

  float hg = hb[2047 * 256 + tid];
  float* cb = ctx + (b * 2048 + k0) * 256 + tid;
#pragma unroll
  for (int kk = 0; kk < 16; kk++) cb[kk * 256] = hg + acc[kk] * rden[kk];
}

// ---------------- init head: m0, s0, log_q0 ----------------
__global__ void init_head(const float* __restrict__ ctx, const float* __restrict__ WT1,
                          const float* __restrict__ bi1, const float* __restrict__ WT2,
                          const float* __restrict__ bi2, const float* __restrict__ eps0,
                          float* __restrict__ m0s0, float* __restrict__ lq0) {
  int b = blockIdx.x;
  int g = threadIdx.x;
  __shared__ float xs[256], his[256], ms[64], red[32];
  xs[g] = ctx[(b * 2048) * 256 + g];
  __syncthreads();
  float acc = bi1[g];
#pragma unroll 8
  for (int k = 0; k < 256; k++) acc = fmaf(WT1[k * 256 + g], xs[k], acc);
  his[g] = silu_f(acc);
  __syncthreads();
  if (g < 64) {
    float a2 = bi2[g];
#pragma unroll 8
    for (int k = 0; k < 256; k++) a2 = fmaf(WT2[k * 64 + g], his[k], a2);
    float v = (g < 32) ? a2 : (softplus_f(a2) + 1e-6f);
    m0s0[b * 64 + g] = v;
    ms[g] = v;
  }
  __syncthreads();
  if (g < 32) {
    float m = ms[g], s = ms[32 + g];
    float c0 = m + s * eps0[b * 32 + g];
    float sc = fmaxf(s, 1e-12f);
    float z = (c0 - m) / sc;
    red[g] = z * z + 2.f * __logf(sc) + LOG2PI_F;
  }
  __syncthreads();
  if (g == 0) {
    float s = 0.f;
    for (int i = 0; i < 32; i++) s += red[i];
    lq0[b] = -0.5f * s;
  }
}

// ---------------- step-head dense layer (M-tile=8) ----------------
__global__ void head_layer(const float* __restrict__ A, const float* __restrict__ WT,
                           const float* __restrict__ bias, const float* __restrict__ wext,
                           const float* __restrict__ tvec, float* __restrict__ C,
                           int N, int act) {
  int m0 = blockIdx.x * 8;
  int g = threadIdx.x;
  __shared__ __align__(16) float As[8][256];
#pragma unroll
  for (int r = 0; r < 8; r++) As[r][g] = A[(m0 + r) * 256 + g];
  __syncthreads();
  if (g < N) {
    float b0 = bias[g];
    float acc[8] = {b0, b0, b0, b0, b0, b0, b0, b0};
    for (int k4 = 0; k4 < 64; k4++) {
      const float* w = WT + (k4 * 4) * N + g;
      float w0v = w[0], w1v = w[N], w2v = w[2 * N], w3v = w[3 * N];
#pragma unroll
      for (int r = 0; r < 8; r++) {
        float4 xv = *(const float4*)(&As[r][k4 * 4]);
        acc[r] = fmaf(w0v, xv.x, acc[r]);
        acc[r] = fmaf(w1v, xv.y, acc[r]);
        acc[r] = fmaf(w2v, xv.z, acc[r]);
        acc[r] = fmaf(w3v, xv.w, acc[r]);
      }
    }
#pragma unroll
    for (int r = 0; r < 8; r++) {
      float a = acc[r];
      if (wext) a = fmaf(tvec[m0 + r], wext[g], a);
      if (act) a = silu_f(a);
      C[(m0 + r) * N + g] = a;
    }
  }
}

// ---------------- OU posterior: parallel segmented scan ----------------
__global__ __launch_bounds__(1024) void ou_kernel(
    const float* __restrict__ params, const float* __restrict__ t,
    const float* __restrict__ eps, const float* __restrict__ eps0,
    const float* __restrict__ m0s0, const float* __restrict__ lq0,
    float* __restrict__ out) {
  const int b = blockIdx.x;
  const int c = threadIdx.x & 31;
  const int s = threadIdx.x >> 5;  // segment 0..31
  const int k0 = s * 64;
  const int k1 = min(k0 + 64, 2047);
  const float* tb = t + b * 2048;

  __shared__ float Ps[32][33], Ss[32][33], Cs[32][33], lqs[32][33];

  float P = 1.f, S = 0.f, lq = 0.f;
  for (int k = k0; k < k1; k++) {
    const float* pr = params + (b * 2048 + k) * 96;
    float mu = pr[c];
    float kap = softplus_f(pr[32 + c]) + 1e-6f;
    float sg = softplus_f(pr[64 + c]) + 1e-6f;
    float dt = fmaxf(tb[k + 1] - tb[k], 1e-6f);
    float A = __expf(-kap * dt);
    float tkd = 2.f * kap * dt;
    float Qe = sg * sg * (1.f - A * A) / fmaxf(2.f * kap, 1e-12f);
    float kd = kap * dt;
    float Qt = sg * sg * dt * (1.f - kd + tkd * tkd * (1.f / 6.f));
    float var = fmaxf((tkd < 1e-6f) ? Qt : Qe, 1e-12f);
    float e = eps[(b * 2047 + k) * 32 + c];
    float d = mu * (1.f - A) + e * sqrtf(var);
    S = fmaf(A, S, d);
    P *= A;
    lq += e * e + __logf(var) + LOG2PI_F;
  }
  Ps[c][s] = P;
  Ss[c][s] = S;
  lqs[c][s] = lq;
  __syncthreads();

  if (s == 0) {
    float m0v = m0s0[b * 64 + c];
    float s0v = m0s0[b * 64 + 32 + c];
    float cc = fmaf(s0v, eps0[b * 32 + c], m0v);
    out[(b * 2048) * 32 + c] = cc;
    float lqt = 0.f;
    for (int i = 0; i < 32; i++) {
      Cs[c][i] = cc;
      cc = fmaf(Ps[c][i], cc, Ss[c][i]);
      lqt += lqs[c][i];
    }
    for (int off = 16; off >= 1; off >>= 1) lqt += __shfl_down(lqt, off, 32);
    if (c == 0) out[8 * 2048 * 32 + b] = lq0[b] - 0.5f * lqt;
  }
  __syncthreads();

  float cc = Cs[c][s];
  for (int k = k0; k < k1; k++) {
    const float* pr = params + (b * 2048 + k) * 96;
    float mu = pr[c];
    float kap = softplus_f(pr[32 + c]) + 1e-6f;
    float sg = softplus_f(pr[64 + c]) + 1e-6f;
    float dt = fmaxf(tb[k + 1] - tb[k], 1e-6f);
    float A = __expf(-kap * dt);
    float tkd = 2.f * kap * dt;
    float Qe = sg * sg * (1.f - A * A) / fmaxf(2.f * kap, 1e-12f);
    float kd = kap * dt;
    float Qt = sg * sg * dt * (1.f - kd + tkd * tkd * (1.f / 6.f));
    float var = fmaxf((tkd < 1e-6f) ? Qt : Qe, 1e-12f);
    float e = eps[(b * 2047 + k) * 32 + c];
    float d = mu * (1.f - A) + e * sqrtf(var);
    cc = fmaf(A, cc, d);
    out[(b * 2048 + k + 1) * 32 + c] = cc;
  }
}

// ---------------- launcher ----------------
extern "C" void kernel_launch(void* const* d_in, const int* in_sizes, int n_in,
                              void* d_out, int out_size, void* d_ws, size_t ws_size,
                              hipStream_t stream) {
  (void)in_sizes; (void)n_in; (void)out_size; (void)ws_size;
  const float* x    = (const float*)d_in[0];
  const float* t    = (const float*)d_in[1];
  const float* eps0 = (const float*)d_in[2];
  const float* eps  = (const float*)d_in[3];
  const float* W_ih = (const float*)d_in[4];
  const float* W_hh = (const float*)d_in[5];
  const float* b_ih = (const float*)d_in[6];
  const float* b_hh = (const float*)d_in[7];
  const float* Wi1  = (const float*)d_in[8];
  const float* bi1  = (const float*)d_in[9];
  const float* Wi2  = (const float*)d_in[10];
  const float* bi2  = (const float*)d_in[11];
  const float* Ws1  = (const float*)d_in[12];
  const float* bs1  = (const float*)d_in[13];
  const float* Ws2  = (const float*)d_in[14];
  const float* bs2  = (const float*)d_in[15];
  const float* Ws3  = (const float*)d_in[16];
  const float* bs3  = (const float*)d_in[17];
  float* out = (float*)d_out;
  float* ws = (float*)d_ws;

  // workspace layout (float offsets)
  float*        WT_ih = ws + 0;                        // 64x768   = 49152
  unsigned int* Wmf   = (unsigned int*)(ws + 49152);   // 98304 dwords (MFMA frags)
  float*        WT1   = ws + 147456;                   // 256x256  = 65536
  float*        WT2   = ws + 212992;                   // 256x64   = 16384
  float*        WTs1  = ws + 229376;                   // 257x256  = 65792
  float*        WTs2  = ws + 295168;                   // 256x256  = 65536
  float*        WTs3  = ws + 360704;                   // 256x96   = 24576
  float*        m0s0  = ws + 385280;                   // 8x64
  float*        lq0   = ws + 385792;                   // 8
  float*        gi    = ws + 385800;                   // 8x2048x768 = 12582912
  float*        h_seq = gi + 12582912;                 // 8x2048x256 = 4194304
  float*        ctx   = h_seq + 4194304;               // 8x2048x256 = 4194304
  // reuse gi region after GRU:
  float*        hs1    = gi;                           // 4194304
  float*        hs2    = gi + 4194304;                 // 4194304
  float*        params = gi + 8388608;                 // 8x2048x96 = 1572864

  // prep
  transpose_k<<<(768 * 64 + 255) / 256, 256, 0, stream>>>(W_ih, WT_ih, 768, 64);
  transpose_k<<<(256 * 256 + 255) / 256, 256, 0, stream>>>(Wi1, WT1, 256, 256);
  transpose_k<<<(64 * 256 + 255) / 256, 256, 0, stream>>>(Wi2, WT2, 64, 256);
  transpose_k<<<(256 * 257 + 255) / 256, 256, 0, stream>>>(Ws1, WTs1, 256, 257);
  transpose_k<<<(256 * 256 + 255) / 256, 256, 0, stream>>>(Ws2, WTs2, 256, 256);
  transpose_k<<<(96 * 256 + 255) / 256, 256, 0, stream>>>(Ws3, WTs3, 96, 256);
  whh_mfma_pack<<<384, 256, 0, stream>>>(W_hh, (unsigned int*)Wmf);

  // pipeline
  gi_gemm<<<2048, 256, 0, stream>>>(x, WT_ih, b_ih, b_hh, gi);
  gru_kernel<<<8, 768, 0, stream>>>((const uint4*)Wmf, gi, b_hh, h_seq);
  attn_kernel<<<1024, 256, 0, stream>>>(h_seq, t, ctx);
  init_head<<<8, 256, 0, stream>>>(ctx, WT1, bi1, WT2, bi2, eps0, m0s0, lq0);
  head_layer<<<2048, 256, 0, stream>>>(ctx, WTs1, bs1, WTs1 + 256 * 256, t, hs1, 256, 1);
  head_layer<<<2048, 256, 0, stream>>>(hs1, WTs2, bs2, nullptr, nullptr, hs2, 256, 1);
  head_layer<<<2048, 256, 0, stream>>>(hs2, WTs3, bs3, nullptr, nullptr, params, 96, 0);
  ou_kernel<<<8, 1024, 0, stream>>>(params, t, eps, eps0, m0s0, lq0, out);
}